// Round 4
// baseline (250.355 us; speedup 1.0000x reference)
//
#include <hip/hip_runtime.h>

typedef _Float16 f16;
typedef _Float16 f16x4 __attribute__((ext_vector_type(4)));
typedef _Float16 f16x8 __attribute__((ext_vector_type(8)));
typedef float f32x4  __attribute__((ext_vector_type(4)));

#define MFMAH(a, b, c) __builtin_amdgcn_mfma_f32_16x16x32_f16(a, b, c, 0, 0, 0)
#define EX2(x) __builtin_amdgcn_exp2f(x)

constexpr int D = 256;
constexpr int S = 4096;
constexpr int BATCH = 4;
constexpr int NROWS = BATCH * S;           // 16384
// softmax runs in exp2 domain: fold log2(e) into the Q scale.
constexpr float SCALE = 0.0625f * 1.44269504088896340736f;
constexpr float DTHR = 6.0f;               // defer-max threshold (log2 units): p <= 64
constexpr size_t NE = (size_t)NROWS * D;   // 4.19M elems

// async global->LDS: per-lane src addr, wave-uniform LDS base (+lane*16 by HW)
__device__ __forceinline__ void gll16(const void* g, void* l) {
  __builtin_amdgcn_global_load_lds(
      (const __attribute__((address_space(1))) unsigned int*)g,
      (__attribute__((address_space(3))) unsigned int*)l, 16, 0, 0);
}

__device__ __forceinline__ float fmax4(float a, float b, float c, float d) {
  return fmaxf(fmaxf(a, b), fmaxf(c, d));
}

// ---------------------------------------------------------------------------
// Prep: W in MFMA-fragment order. frag f = ct*8+kc (1KB each), lane-contiguous:
// Wf[m][f][lane][j] = w_m[(kc*32+quad*8+j)][ct*16+l15]   (fp16)
// ---------------------------------------------------------------------------
__global__ __launch_bounds__(256)
void prep_wt_kernel(const float* __restrict__ wq, const float* __restrict__ wk,
                    const float* __restrict__ wv, const float* __restrict__ wo,
                    f16* __restrict__ Wf)
{
  const int m = blockIdx.y;
  const float* w = (m == 0) ? wq : (m == 1) ? wk : (m == 2) ? wv : wo;
  int id = blockIdx.x * 256 + threadIdx.x;    // 0..8191 (one 16B chunk each)
  int f = id >> 6, lane = id & 63;
  int ct = f >> 3, kc = f & 7;
  int l15 = lane & 15, quad = lane >> 4;
  const float* src = w + (kc * 32 + quad * 8) * 256 + ct * 16 + l15;
  f16x8 v;
#pragma unroll
  for (int j = 0; j < 8; ++j) v[j] = (f16)src[j * 256];
  *(f16x8*)(Wf + ((size_t)m << 16) + (size_t)id * 8) = v;
}

// ---------------------------------------------------------------------------
// QKV projection via MFMA. B fragments read directly from L2 (fragment-ordered
// Wf) -> barrier-free main loop. LDS only for transposed coalesced epilogues.
// ---------------------------------------------------------------------------
__global__ __launch_bounds__(256)
void qkv_mfma_kernel(const float* __restrict__ in, const f16* __restrict__ Wt,
                     const float* __restrict__ bq, const float* __restrict__ bk,
                     const float* __restrict__ bv,
                     f16* __restrict__ Qh, f16* __restrict__ Kf, f16* __restrict__ Vf)
{
  __shared__ __align__(16) char smem[32768];   // epilogue transpose buffer
  const int m = blockIdx.y;
  const int tid = threadIdx.x, lane = tid & 63, w = tid >> 6;
  const int l15 = lane & 15, quad = lane >> 4;
  const int row0 = blockIdx.x * 64 + w * 16;
  const f16* Wm = Wt + ((size_t)m << 16);
  const float* bias = (m == 0) ? bq : (m == 1) ? bk : bv;

  // ---- A fragments: 16 rows of `in`, fp32 -> fp16 up front
  f16x8 af[8];
  {
    const float* arow = in + (size_t)(row0 + l15) * 768 + m * 256 + quad * 8;
#pragma unroll
    for (int kc = 0; kc < 8; ++kc) {
      float4 a0 = *(const float4*)(arow + kc * 32);
      float4 a1 = *(const float4*)(arow + kc * 32 + 4);
      f16x8 a;
      a[0] = (f16)a0.x; a[1] = (f16)a0.y; a[2] = (f16)a0.z; a[3] = (f16)a0.w;
      a[4] = (f16)a1.x; a[5] = (f16)a1.y; a[6] = (f16)a1.z; a[7] = (f16)a1.w;
      af[kc] = a;
    }
  }

  f32x4 acc[16];
#pragma unroll
  for (int ct = 0; ct < 16; ++ct) acc[ct] = (f32x4){0.f, 0.f, 0.f, 0.f};

  // ---- main loop: direct L2 B-frag loads, no barriers
#pragma unroll
  for (int kc = 0; kc < 8; ++kc) {
#pragma unroll
    for (int ct = 0; ct < 16; ++ct) {
      f16x8 b = *(const f16x8*)(Wm + (size_t)(ct * 8 + kc) * 512 + lane * 8);
      acc[ct] = MFMAH(af[kc], b, acc[ct]);
    }
  }

  const int b_ = row0 >> 12;

  if (m == 0) {
    f16* ws = (f16*)(smem + w * 8192);
#pragma unroll
    for (int ct = 0; ct < 16; ++ct) {
      float bct = bias[ct * 16 + l15];
#pragma unroll
      for (int r = 0; r < 4; ++r)
        ws[(quad * 4 + r) * 256 + ct * 16 + l15] = (f16)((acc[ct][r] + bct) * SCALE);
    }
    f16* dst = Qh + (size_t)row0 * 256;
#pragma unroll
    for (int i = 0; i < 8; ++i)
      *(uint4*)(dst + lane * 8 + i * 512) = *(const uint4*)(ws + lane * 8 + i * 512);
  } else if (m == 1) {
    f16* ws = (f16*)(smem + w * 8192);
#pragma unroll
    for (int ct = 0; ct < 16; ++ct) {
      float bct = bias[ct * 16 + l15];
      int base = (ct >> 1) * 512 + ((ct & 1) * 2 + (l15 >> 3)) * 128 + (l15 & 7);
#pragma unroll
      for (int r = 0; r < 4; ++r)
        ws[base + (quad * 4 + r) * 8] = (f16)(acc[ct][r] + bct);
    }
    const int g = (row0 & 4095) >> 4;
    f16* dst = Kf + ((size_t)(b_ * 256 + g)) * 8 * 512;
#pragma unroll
    for (int i = 0; i < 8; ++i)
      *(uint4*)(dst + lane * 8 + i * 512) = *(const uint4*)(ws + lane * 8 + i * 512);
  } else {
    const int t = w & 1;
    f16* ws = (f16*)(smem + (w >> 1) * 16384);
#pragma unroll
    for (int ct = 0; ct < 16; ++ct) {
      float bct = bias[ct * 16 + l15];
      int base = ct * 512 + quad * 128 + l15 * 8 + t * 4;
#pragma unroll
      for (int r = 0; r < 4; ++r)
        ws[base + r] = (f16)(acc[ct][r] + bct);
    }
    __syncthreads();
    const int gv0 = ((blockIdx.x * 64) & 4095) >> 5;
    f16* dst = Vf + ((size_t)(b_ * 128 + gv0)) * 16 * 512;
    const f16* src = (const f16*)smem;
#pragma unroll
    for (int i = 0; i < 8; ++i)
      *(uint4*)(dst + tid * 8 + i * 2048) = *(const uint4*)(src + tid * 8 + i * 2048);
  }
}

// ---------------------------------------------------------------------------
// fp16 MFMA flash attention. 512 blocks x 256 thr, split-K=4, 32-key tiles.
// Round-4 change: V is NOT staged in LDS. PV reads V fragments directly from
// global (fragment-ordered Vf, L2-resident: each 512KB slice shared by 32
// blocks). Halves LDS read traffic (each wave read the full V tile from LDS
// redundantly), halves gll16 staging, halves LDS footprint (32KB). V loads
// depend only on `it` -> compiler hoists them above softmax (latency hidden).
// K stays LDS-staged (dbuf, gll16): QK needs it immediately after barrier.
// ---------------------------------------------------------------------------
__global__ __launch_bounds__(256, 2)
void attn6_kernel(const f16* __restrict__ Qh, const char* __restrict__ Kf,
                  const char* __restrict__ Vf,
                  f16* __restrict__ Pp, float* __restrict__ Mp, float* __restrict__ Lp)
{
  __shared__ __align__(16) char KVs[2][16384];   // K 16 frags only (dbuf)

  const int tid = threadIdx.x, lane = tid & 63, w = tid >> 6;
  const int l15 = lane & 15, quad = lane >> 4;

  const int bx    = blockIdx.x;
  const int combo = bx & 15;
  const int b     = combo & 3;
  const int kz    = combo >> 2;
  const int qb    = bx >> 4;                   // 0..31
  const int qrow0 = qb * 128 + w * 32;
  const int grow  = b * 4096 + qrow0;

  f16x8 qf[2][8];
#pragma unroll
  for (int sub = 0; sub < 2; ++sub) {
    const size_t qoff = (size_t)(grow + sub * 16 + l15) * 256 + quad * 8;
#pragma unroll
    for (int kc = 0; kc < 8; ++kc)
      qf[sub][kc] = *(const f16x8*)(Qh + qoff + kc * 32);
  }

  const char* kg[4];
#pragma unroll
  for (int i = 0; i < 4; ++i) {
    int f = 4 * w + i;
    kg[i] = Kf + (((size_t)(b * 256 + kz * 64 + (f >> 3))) * 8 + (f & 7)) * 1024
               + lane * 16;
  }
  // V fragment base for this (b,kz): frag ct of tile `it` at vb + it*16384 + ct*1024
  const char* vb = Vf + ((size_t)(b * 128 + kz * 32) * 16) * 1024 + lane * 16;

  auto stage = [&](int buf) {
    char* base = &KVs[buf][0];
#pragma unroll
    for (int i = 0; i < 4; ++i) { gll16(kg[i], base + (4 * w + i) * 1024); kg[i] += 16384; }
  };

  f32x4 o0[16], o1[16];
#pragma unroll
  for (int ct = 0; ct < 16; ++ct) {
    o0[ct] = (f32x4){0.f, 0.f, 0.f, 0.f};
    o1[ct] = (f32x4){0.f, 0.f, 0.f, 0.f};
  }
  float m0 = -3.0e38f, m1 = -3.0e38f;
  float lp0 = 0.f, lp1 = 0.f;                  // per-lane partial denominators

  stage(0);

  for (int it = 0; it < 32; ++it) {
    __syncthreads();
    if (it < 31) stage((it + 1) & 1);
    const char* Bf = &KVs[it & 1][0];
    const char* Vg = vb + (size_t)it * 16384;

    f32x4 sA0 = (f32x4){0.f,0.f,0.f,0.f}, sB0 = (f32x4){0.f,0.f,0.f,0.f};
    f32x4 sA1 = (f32x4){0.f,0.f,0.f,0.f}, sB1 = (f32x4){0.f,0.f,0.f,0.f};
    __builtin_amdgcn_s_setprio(1);
#pragma unroll
    for (int kc = 0; kc < 8; ++kc) {
      f16x8 kA = *(const f16x8*)(Bf + kc * 1024 + lane * 16);
      f16x8 kB = *(const f16x8*)(Bf + 8192 + kc * 1024 + lane * 16);
      sA0 = MFMAH(kA, qf[0][kc], sA0);
      sA1 = MFMAH(kA, qf[1][kc], sA1);
      sB0 = MFMAH(kB, qf[0][kc], sB0);
      sB1 = MFMAH(kB, qf[1][kc], sB1);
    }
    __builtin_amdgcn_s_setprio(0);

    // per-lane local maxes (no cross-lane traffic)
    float lm0 = fmaxf(fmax4(sA0[0], sA0[1], sA0[2], sA0[3]),
                      fmax4(sB0[0], sB0[1], sB0[2], sB0[3]));
    float lm1 = fmaxf(fmax4(sA1[0], sA1[1], sA1[2], sA1[3]),
                      fmax4(sB1[0], sB1[1], sB1[2], sB1[3]));

    // rare (first iters only): full reduce + rescale, inside one branch
    if (__any((lm0 > m0 + DTHR) | (lm1 > m1 + DTHR))) {
      float t0 = fmaxf(lm0, __shfl_xor(lm0, 16));
      t0 = fmaxf(t0, __shfl_xor(t0, 32));
      float t1 = fmaxf(lm1, __shfl_xor(lm1, 16));
      t1 = fmaxf(t1, __shfl_xor(t1, 32));
      float mn0 = fmaxf(m0, t0), mn1 = fmaxf(m1, t1);
      float al0 = EX2(m0 - mn0), al1 = EX2(m1 - mn1);
      {
        float a0 = __shfl(al0, (quad << 2) + 0);
        float a1 = __shfl(al0, (quad << 2) + 1);
        float a2 = __shfl(al0, (quad << 2) + 2);
        float a3 = __shfl(al0, (quad << 2) + 3);
#pragma unroll
        for (int ct = 0; ct < 16; ++ct) {
          o0[ct][0] *= a0; o0[ct][1] *= a1; o0[ct][2] *= a2; o0[ct][3] *= a3;
        }
      }
      {
        float a0 = __shfl(al1, (quad << 2) + 0);
        float a1 = __shfl(al1, (quad << 2) + 1);
        float a2 = __shfl(al1, (quad << 2) + 2);
        float a3 = __shfl(al1, (quad << 2) + 3);
#pragma unroll
        for (int ct = 0; ct < 16; ++ct) {
          o1[ct][0] *= a0; o1[ct][1] *= a1; o1[ct][2] *= a2; o1[ct][3] *= a3;
        }
      }
      lp0 *= al0;  lp1 *= al1;      // per-lane partials: lane's own q factor
      m0 = mn0;    m1 = mn1;
    }

    // branch-free: exp chains (independent) + PV — one scheduling region
    f16x8 ph0, ph1;
    float ps0 = 0.f, ps1 = 0.f;
#pragma unroll
    for (int r = 0; r < 4; ++r) {
      float pa = EX2(sA0[r] - m0);
      float pb = EX2(sB0[r] - m0);
      ph0[r] = (f16)pa;  ph0[r + 4] = (f16)pb;
      ps0 += pa + pb;
    }
#pragma unroll
    for (int r = 0; r < 4; ++r) {
      float pa = EX2(sA1[r] - m1);
      float pb = EX2(sB1[r] - m1);
      ph1[r] = (f16)pa;  ph1[r + 4] = (f16)pb;
      ps1 += pa + pb;
    }
    lp0 += ps0;  lp1 += ps1;

    // PV: V fragments straight from L2 (independent of softmax -> hoistable)
    __builtin_amdgcn_s_setprio(1);
#pragma unroll
    for (int ct = 0; ct < 16; ++ct) {
      f16x8 vf = *(const f16x8*)(Vg + ct * 1024);
      o0[ct] = MFMAH(ph0, vf, o0[ct]);
      o1[ct] = MFMAH(ph1, vf, o1[ct]);
    }
    __builtin_amdgcn_s_setprio(0);
  }

  // epilogue: single shuffle-reduce of the deferred denominators
  float l0 = lp0 + __shfl_xor(lp0, 16);
  l0 += __shfl_xor(l0, 32);
  float l1 = lp1 + __shfl_xor(lp1, 16);
  l1 += __shfl_xor(l1, 32);

  f16* Od = Pp + (size_t)kz * NE;
#pragma unroll
  for (int r = 0; r < 4; ++r) {
    const size_t ro0 = (size_t)(grow + quad * 4 + r) * 256 + l15;
    const size_t ro1 = (size_t)(grow + 16 + quad * 4 + r) * 256 + l15;
#pragma unroll
    for (int ct = 0; ct < 16; ++ct) {
      Od[ro0 + ct * 16] = (f16)o0[ct][r];
      Od[ro1 + ct * 16] = (f16)o1[ct][r];
    }
  }
  if (lane < 16) {
    Mp[kz * NROWS + grow + l15] = m0;
    Lp[kz * NROWS + grow + l15] = l0;
    Mp[kz * NROWS + grow + 16 + l15] = m1;
    Lp[kz * NROWS + grow + 16 + l15] = l1;
  }
}

// ---------------------------------------------------------------------------
// Fused split-K merge + output projection. 512 blocks x 32 rows.
// B fragments read directly from L2 (fragment-ordered Wf); single barrier.
// ---------------------------------------------------------------------------
__global__ __launch_bounds__(256)
void oproj_mfma_kernel(const f16* __restrict__ Pp, const float* __restrict__ Mp,
                       const float* __restrict__ Lp, const f16* __restrict__ Wto,
                       const float* __restrict__ bo, float* __restrict__ out)
{
  __shared__ f16 xs[32][264];                   // 16.5 KB (padded)
  const int tid = threadIdx.x, lane = tid & 63, w = tid >> 6;
  const int l15 = lane & 15, quad = lane >> 4;
  const int rb = blockIdx.x * 32;

  // ---- merge prologue: 32 rows x 256 cols, 4-way split-K (exp2 domain)
  const int c4 = (tid & 63) * 4;
  const int rsub = tid >> 6;
#pragma unroll
  for (int e = 0; e < 8; ++e) {
    int rl = e * 4 + rsub;
    int row = rb + rl;
    float m[4], l[4];
#pragma unroll
    for (int z = 0; z < 4; ++z) {
      m[z] = Mp[z * NROWS + row];
      l[z] = Lp[z * NROWS + row];
    }
    float mm = fmaxf(fmaxf(m[0], m[1]), fmaxf(m[2], m[3]));
    float wz[4], denom = 0.f;
#pragma unroll
    for (int z = 0; z < 4; ++z) { wz[z] = EX2(m[z] - mm); denom += wz[z] * l[z]; }
    float inv = 1.0f / denom;
    float s0 = 0.f, s1 = 0.f, s2 = 0.f, s3 = 0.f;
#pragma unroll
    for (int z = 0; z < 4; ++z) {
      f16x4 h = *(const f16x4*)(Pp + (size_t)z * NE + (size_t)row * 256 + c4);
      s0 += wz[z] * (float)h[0];
      s1 += wz[z] * (float)h[1];
      s2 += wz[z] * (float)h[2];
      s3 += wz[z] * (float)h[3];
    }
    f16x4 xv;
    xv[0] = (f16)(s0 * inv); xv[1] = (f16)(s1 * inv);
    xv[2] = (f16)(s2 * inv); xv[3] = (f16)(s3 * inv);
    *(f16x4*)&xs[rl][c4] = xv;
  }
  __syncthreads();                       // xs ready

  // ---- GEMM: wave w -> rows (w&1)*16, ct group (w>>1)*8; B frags from L2
  const int rw = (w & 1) * 16;
  const int cg = (w >> 1) * 8;
  f32x4 acc[8];
#pragma unroll
  for (int c = 0; c < 8; ++c) acc[c] = (f32x4){0.f, 0.f, 0.f, 0.f};

#pragma unroll
  for (int kc = 0; kc < 8; ++kc) {
    f16x8 a = *(const f16x8*)&xs[rw + l15][kc * 32 + quad * 8];
#pragma unroll
    for (int c = 0; c < 8; ++c) {
      f16x8 b = *(const f16x8*)(Wto + (size_t)((cg + c) * 8 + kc) * 512 + lane * 8);
      acc[c] = MFMAH(a, b, acc[c]);
    }
  }

#pragma unroll
  for (int c = 0; c < 8; ++c) {
    int col = (cg + c) * 16 + l15;
    float bct = bo[col];
#pragma unroll
    for (int r = 0; r < 4; ++r)
      out[(size_t)(rb + rw + quad * 4 + r) * 256 + col] = acc[c][r] + bct;
  }
}

// ---------------------------------------------------------------------------
extern "C" void kernel_launch(void* const* d_in, const int* in_sizes, int n_in,
                              void* d_out, int out_size, void* d_ws, size_t ws_size,
                              hipStream_t stream)
{
  const float* inp = (const float*)d_in[0];
  const float* wq  = (const float*)d_in[1];
  const float* bq  = (const float*)d_in[2];
  const float* wk  = (const float*)d_in[3];
  const float* bk  = (const float*)d_in[4];
  const float* wv  = (const float*)d_in[5];
  const float* bv  = (const float*)d_in[6];
  const float* wo  = (const float*)d_in[7];
  const float* bo  = (const float*)d_in[8];
  float* out = (float*)d_out;

  // ws (~60 MB): Qh, Kf, Vf (NE f16), Wt (4*65536 f16 frag-ordered), Pp, m/l
  f16* Qh = (f16*)d_ws;
  f16* Kf = Qh + NE;
  f16* Vf = Kf + NE;
  f16* Wt = Vf + NE;
  f16* Pp = Wt + 4 * 65536;
  float* Mp = (float*)(Pp + 4 * NE);
  float* Lp = Mp + 4 * NROWS;

  prep_wt_kernel<<<dim3(32, 4), 256, 0, stream>>>(wq, wk, wv, wo, Wt);

  qkv_mfma_kernel<<<dim3(256, 3), 256, 0, stream>>>(
      inp, Wt, bq, bk, bv, Qh, Kf, Vf);

  attn6_kernel<<<512, 256, 0, stream>>>(Qh, (const char*)Kf, (const char*)Vf,
                                        Pp, Mp, Lp);

  oproj_mfma_kernel<<<512, 256, 0, stream>>>(Pp, Mp, Lp, Wt + 3 * 65536, bo, out);
}

// Round 5
// 216.294 us; speedup vs baseline: 1.1575x; 1.1575x over previous
//
#include <hip/hip_runtime.h>

typedef _Float16 f16;
typedef _Float16 f16x4 __attribute__((ext_vector_type(4)));
typedef _Float16 f16x8 __attribute__((ext_vector_type(8)));
typedef float f32x4  __attribute__((ext_vector_type(4)));

#define MFMAH(a, b, c) __builtin_amdgcn_mfma_f32_16x16x32_f16(a, b, c, 0, 0, 0)
#define EX2(x) __builtin_amdgcn_exp2f(x)

constexpr int D = 256;
constexpr int S = 4096;
constexpr int BATCH = 4;
constexpr int NROWS = BATCH * S;           // 16384
// softmax runs in exp2 domain: fold log2(e) into the Q scale.
constexpr float SCALE = 0.0625f * 1.44269504088896340736f;
constexpr float DTHR = 6.0f;               // defer-max threshold (log2 units): p <= 64
constexpr size_t NE = (size_t)NROWS * D;   // 4.19M elems

// async global->LDS: per-lane src addr, wave-uniform LDS base (+lane*16 by HW)
__device__ __forceinline__ void gll16(const void* g, void* l) {
  __builtin_amdgcn_global_load_lds(
      (const __attribute__((address_space(1))) unsigned int*)g,
      (__attribute__((address_space(3))) unsigned int*)l, 16, 0, 0);
}

__device__ __forceinline__ float fmax4(float a, float b, float c, float d) {
  return fmaxf(fmaxf(a, b), fmaxf(c, d));
}

// ---------------------------------------------------------------------------
// Prep: W in MFMA-fragment order. frag f = ct*8+kc (1KB each), lane-contiguous:
// Wf[m][f][lane][j] = w_m[(kc*32+quad*8+j)][ct*16+l15]   (fp16)
// ---------------------------------------------------------------------------
__global__ __launch_bounds__(256)
void prep_wt_kernel(const float* __restrict__ wq, const float* __restrict__ wk,
                    const float* __restrict__ wv, const float* __restrict__ wo,
                    f16* __restrict__ Wf)
{
  const int m = blockIdx.y;
  const float* w = (m == 0) ? wq : (m == 1) ? wk : (m == 2) ? wv : wo;
  int id = blockIdx.x * 256 + threadIdx.x;    // 0..8191 (one 16B chunk each)
  int f = id >> 6, lane = id & 63;
  int ct = f >> 3, kc = f & 7;
  int l15 = lane & 15, quad = lane >> 4;
  const float* src = w + (kc * 32 + quad * 8) * 256 + ct * 16 + l15;
  f16x8 v;
#pragma unroll
  for (int j = 0; j < 8; ++j) v[j] = (f16)src[j * 256];
  *(f16x8*)(Wf + ((size_t)m << 16) + (size_t)id * 8) = v;
}

// ---------------------------------------------------------------------------
// QKV projection via MFMA. B fragments read directly from L2 (fragment-ordered
// Wf) -> barrier-free main loop. LDS only for transposed coalesced epilogues.
// ---------------------------------------------------------------------------
__global__ __launch_bounds__(256)
void qkv_mfma_kernel(const float* __restrict__ in, const f16* __restrict__ Wt,
                     const float* __restrict__ bq, const float* __restrict__ bk,
                     const float* __restrict__ bv,
                     f16* __restrict__ Qh, f16* __restrict__ Kf, f16* __restrict__ Vf)
{
  __shared__ __align__(16) char smem[32768];   // epilogue transpose buffer
  const int m = blockIdx.y;
  const int tid = threadIdx.x, lane = tid & 63, w = tid >> 6;
  const int l15 = lane & 15, quad = lane >> 4;
  const int row0 = blockIdx.x * 64 + w * 16;
  const f16* Wm = Wt + ((size_t)m << 16);
  const float* bias = (m == 0) ? bq : (m == 1) ? bk : bv;

  // ---- A fragments: 16 rows of `in`, fp32 -> fp16 up front
  f16x8 af[8];
  {
    const float* arow = in + (size_t)(row0 + l15) * 768 + m * 256 + quad * 8;
#pragma unroll
    for (int kc = 0; kc < 8; ++kc) {
      float4 a0 = *(const float4*)(arow + kc * 32);
      float4 a1 = *(const float4*)(arow + kc * 32 + 4);
      f16x8 a;
      a[0] = (f16)a0.x; a[1] = (f16)a0.y; a[2] = (f16)a0.z; a[3] = (f16)a0.w;
      a[4] = (f16)a1.x; a[5] = (f16)a1.y; a[6] = (f16)a1.z; a[7] = (f16)a1.w;
      af[kc] = a;
    }
  }

  f32x4 acc[16];
#pragma unroll
  for (int ct = 0; ct < 16; ++ct) acc[ct] = (f32x4){0.f, 0.f, 0.f, 0.f};

  // ---- main loop: direct L2 B-frag loads, no barriers
#pragma unroll
  for (int kc = 0; kc < 8; ++kc) {
#pragma unroll
    for (int ct = 0; ct < 16; ++ct) {
      f16x8 b = *(const f16x8*)(Wm + (size_t)(ct * 8 + kc) * 512 + lane * 8);
      acc[ct] = MFMAH(af[kc], b, acc[ct]);
    }
  }

  const int b_ = row0 >> 12;

  if (m == 0) {
    f16* ws = (f16*)(smem + w * 8192);
#pragma unroll
    for (int ct = 0; ct < 16; ++ct) {
      float bct = bias[ct * 16 + l15];
#pragma unroll
      for (int r = 0; r < 4; ++r)
        ws[(quad * 4 + r) * 256 + ct * 16 + l15] = (f16)((acc[ct][r] + bct) * SCALE);
    }
    f16* dst = Qh + (size_t)row0 * 256;
#pragma unroll
    for (int i = 0; i < 8; ++i)
      *(uint4*)(dst + lane * 8 + i * 512) = *(const uint4*)(ws + lane * 8 + i * 512);
  } else if (m == 1) {
    f16* ws = (f16*)(smem + w * 8192);
#pragma unroll
    for (int ct = 0; ct < 16; ++ct) {
      float bct = bias[ct * 16 + l15];
      int base = (ct >> 1) * 512 + ((ct & 1) * 2 + (l15 >> 3)) * 128 + (l15 & 7);
#pragma unroll
      for (int r = 0; r < 4; ++r)
        ws[base + (quad * 4 + r) * 8] = (f16)(acc[ct][r] + bct);
    }
    const int g = (row0 & 4095) >> 4;
    f16* dst = Kf + ((size_t)(b_ * 256 + g)) * 8 * 512;
#pragma unroll
    for (int i = 0; i < 8; ++i)
      *(uint4*)(dst + lane * 8 + i * 512) = *(const uint4*)(ws + lane * 8 + i * 512);
  } else {
    const int t = w & 1;
    f16* ws = (f16*)(smem + (w >> 1) * 16384);
#pragma unroll
    for (int ct = 0; ct < 16; ++ct) {
      float bct = bias[ct * 16 + l15];
      int base = ct * 512 + quad * 128 + l15 * 8 + t * 4;
#pragma unroll
      for (int r = 0; r < 4; ++r)
        ws[base + r] = (f16)(acc[ct][r] + bct);
    }
    __syncthreads();
    const int gv0 = ((blockIdx.x * 64) & 4095) >> 5;
    f16* dst = Vf + ((size_t)(b_ * 128 + gv0)) * 16 * 512;
    const f16* src = (const f16*)smem;
#pragma unroll
    for (int i = 0; i < 8; ++i)
      *(uint4*)(dst + tid * 8 + i * 2048) = *(const uint4*)(src + tid * 8 + i * 2048);
  }
}

// ---------------------------------------------------------------------------
// fp16 MFMA flash attention. 512 blocks x 256 thr, split-K=4, 32-key tiles.
// Round-5: rotated software pipeline. Iteration body (one barrier/iter) is a
// single scheduling region: softmax(it) [VALU] ∥ QK(it+1) [MFMA+LDS] ∥ PV(it)
// [MFMA+LDS]. QK(it+1) is independent of softmax(it)/PV(it), so the scheduler
// fills softmax bubbles with MFMA work. Scores sA/sB carried across the body
// boundary (+16 VGPR), offset by collapsing 8 staging pointers to 2 (i*1024
// folds into the gll16 address). K staged 2 tiles ahead (dbuf), V staged 1
// tile ahead (dbuf): all RAW drained by the per-iter barrier; WAR reads of
// each overwritten slot complete before the issuing barrier. Softmax = R2
// verbatim (best measured: 85.4us). LDS 64KB, 2 blocks/CU unchanged.
// ---------------------------------------------------------------------------
__global__ __launch_bounds__(256, 2)
void attn6_kernel(const f16* __restrict__ Qh, const char* __restrict__ Kf,
                  const char* __restrict__ Vf,
                  f16* __restrict__ Pp, float* __restrict__ Mp, float* __restrict__ Lp)
{
  __shared__ __align__(16) char Kb[2][16384];
  __shared__ __align__(16) char Vb[2][16384];

  const int tid = threadIdx.x, lane = tid & 63, w = tid >> 6;
  const int l15 = lane & 15, quad = lane >> 4;

  const int bx    = blockIdx.x;
  const int combo = bx & 15;
  const int b     = combo & 3;
  const int kz    = combo >> 2;
  const int qb    = bx >> 4;                   // 0..31
  const int qrow0 = qb * 128 + w * 32;
  const int grow  = b * 4096 + qrow0;

  f16x8 qf[2][8];
#pragma unroll
  for (int sub = 0; sub < 2; ++sub) {
    const size_t qoff = (size_t)(grow + sub * 16 + l15) * 256 + quad * 8;
#pragma unroll
    for (int kc = 0; kc < 8; ++kc)
      qf[sub][kc] = *(const f16x8*)(Qh + qoff + kc * 32);
  }

  // wave-contiguous fragment bases (frags 4w..4w+3 are contiguous in both
  // Kf and Vf layouts; per-i offset i*1024 folds into the load address)
  const int f0 = 4 * w;
  const char* kg = Kf + (((size_t)(b * 256 + kz * 64 + (f0 >> 3))) * 8 + (f0 & 7)) * 1024
                      + lane * 16;
  const char* vg = Vf + (((size_t)(b * 128 + kz * 32)) * 16 + f0) * 1024 + lane * 16;

  auto stageK = [&](int buf) {
    char* base = &Kb[buf][0] + f0 * 1024;
#pragma unroll
    for (int i = 0; i < 4; ++i) gll16(kg + i * 1024, base + i * 1024);
    kg += 16384;
  };
  auto stageV = [&](int buf) {
    char* base = &Vb[buf][0] + f0 * 1024;
#pragma unroll
    for (int i = 0; i < 4; ++i) gll16(vg + i * 1024, base + i * 1024);
    vg += 16384;
  };

  f32x4 o0[16], o1[16];
#pragma unroll
  for (int ct = 0; ct < 16; ++ct) {
    o0[ct] = (f32x4){0.f, 0.f, 0.f, 0.f};
    o1[ct] = (f32x4){0.f, 0.f, 0.f, 0.f};
  }
  float m0 = -3.0e38f, m1 = -3.0e38f, l0 = 0.f, l1 = 0.f;

  // prologue: K(0),K(1),V(0) staged; QK(0) computed
  stageK(0); stageK(1); stageV(0);
  __syncthreads();

  f32x4 sA0 = (f32x4){0.f,0.f,0.f,0.f}, sB0 = (f32x4){0.f,0.f,0.f,0.f};
  f32x4 sA1 = (f32x4){0.f,0.f,0.f,0.f}, sB1 = (f32x4){0.f,0.f,0.f,0.f};
  {
    const char* Bf = &Kb[0][0];
    __builtin_amdgcn_s_setprio(1);
#pragma unroll
    for (int kc = 0; kc < 8; ++kc) {
      f16x8 kA = *(const f16x8*)(Bf + kc * 1024 + lane * 16);
      f16x8 kB = *(const f16x8*)(Bf + 8192 + kc * 1024 + lane * 16);
      sA0 = MFMAH(kA, qf[0][kc], sA0);
      sA1 = MFMAH(kA, qf[1][kc], sA1);
      sB0 = MFMAH(kB, qf[0][kc], sB0);
      sB1 = MFMAH(kB, qf[1][kc], sB1);
    }
    __builtin_amdgcn_s_setprio(0);
  }

  for (int it = 0; it < 32; ++it) {
    __syncthreads();                 // drains: K(it+1), V(it) staged; WAR ok
    if (it < 30) stageK(it & 1);       // K(it+2) -> Kb[it&1]
    if (it < 31) stageV((it + 1) & 1); // V(it+1) -> Vb[(it+1)&1]

    // ---- softmax(it) on carried sA/sB (R2 verbatim) ----
    f16x8 ph0, ph1;
    {
      float t = fmaxf(fmaxf(fmaxf(sA0[0], sA0[1]), fmaxf(sA0[2], sA0[3])),
                      fmaxf(fmaxf(sB0[0], sB0[1]), fmaxf(sB0[2], sB0[3])));
      t = fmaxf(t, __shfl_xor(t, 16));
      t = fmaxf(t, __shfl_xor(t, 32));
      if (__any(t > m0 + DTHR)) {          // rare after iter 0 (defer-max)
        float mn = fmaxf(m0, t);
        float al = EX2(m0 - mn);
        float a0 = __shfl(al, (quad << 2) + 0);
        float a1 = __shfl(al, (quad << 2) + 1);
        float a2 = __shfl(al, (quad << 2) + 2);
        float a3 = __shfl(al, (quad << 2) + 3);
#pragma unroll
        for (int ct = 0; ct < 16; ++ct) {
          o0[ct][0] *= a0; o0[ct][1] *= a1; o0[ct][2] *= a2; o0[ct][3] *= a3;
        }
        l0 *= al;
        m0 = mn;
      }
      float ps = 0.f;
#pragma unroll
      for (int r = 0; r < 4; ++r) {
        float pa = EX2(sA0[r] - m0);
        float pb = EX2(sB0[r] - m0);
        ph0[r] = (f16)pa;  ph0[r + 4] = (f16)pb;
        ps += pa + pb;
      }
      ps += __shfl_xor(ps, 16);
      ps += __shfl_xor(ps, 32);
      l0 += ps;
    }
    {
      float t = fmaxf(fmaxf(fmaxf(sA1[0], sA1[1]), fmaxf(sA1[2], sA1[3])),
                      fmaxf(fmaxf(sB1[0], sB1[1]), fmaxf(sB1[2], sB1[3])));
      t = fmaxf(t, __shfl_xor(t, 16));
      t = fmaxf(t, __shfl_xor(t, 32));
      if (__any(t > m1 + DTHR)) {          // rare after iter 0 (defer-max)
        float mn = fmaxf(m1, t);
        float al = EX2(m1 - mn);
        float a0 = __shfl(al, (quad << 2) + 0);
        float a1 = __shfl(al, (quad << 2) + 1);
        float a2 = __shfl(al, (quad << 2) + 2);
        float a3 = __shfl(al, (quad << 2) + 3);
#pragma unroll
        for (int ct = 0; ct < 16; ++ct) {
          o1[ct][0] *= a0; o1[ct][1] *= a1; o1[ct][2] *= a2; o1[ct][3] *= a3;
        }
        l1 *= al;
        m1 = mn;
      }
      float ps = 0.f;
#pragma unroll
      for (int r = 0; r < 4; ++r) {
        float pa = EX2(sA1[r] - m1);
        float pb = EX2(sB1[r] - m1);
        ph1[r] = (f16)pa;  ph1[r + 4] = (f16)pb;
        ps += pa + pb;
      }
      ps += __shfl_xor(ps, 16);
      ps += __shfl_xor(ps, 32);
      l1 += ps;
    }

    // ---- QK(it+1): independent of softmax/PV; fills VALU bubbles ----
    f32x4 nA0 = (f32x4){0.f,0.f,0.f,0.f}, nB0 = (f32x4){0.f,0.f,0.f,0.f};
    f32x4 nA1 = (f32x4){0.f,0.f,0.f,0.f}, nB1 = (f32x4){0.f,0.f,0.f,0.f};
    if (it < 31) {
      const char* Bf = &Kb[(it + 1) & 1][0];
      __builtin_amdgcn_s_setprio(1);
#pragma unroll
      for (int kc = 0; kc < 8; ++kc) {
        f16x8 kA = *(const f16x8*)(Bf + kc * 1024 + lane * 16);
        f16x8 kB = *(const f16x8*)(Bf + 8192 + kc * 1024 + lane * 16);
        nA0 = MFMAH(kA, qf[0][kc], nA0);
        nA1 = MFMAH(kA, qf[1][kc], nA1);
        nB0 = MFMAH(kB, qf[0][kc], nB0);
        nB1 = MFMAH(kB, qf[1][kc], nB1);
      }
      __builtin_amdgcn_s_setprio(0);
    }

    // ---- PV(it) ----
    const char* Vg = &Vb[it & 1][0];
    __builtin_amdgcn_s_setprio(1);
#pragma unroll
    for (int ct = 0; ct < 16; ++ct) {
      f16x8 vf = *(const f16x8*)(Vg + ct * 1024 + lane * 16);
      o0[ct] = MFMAH(ph0, vf, o0[ct]);
      o1[ct] = MFMAH(ph1, vf, o1[ct]);
    }
    __builtin_amdgcn_s_setprio(0);

    sA0 = nA0; sB0 = nB0; sA1 = nA1; sB1 = nB1;
  }

  f16* Od = Pp + (size_t)kz * NE;
#pragma unroll
  for (int r = 0; r < 4; ++r) {
    const size_t ro0 = (size_t)(grow + quad * 4 + r) * 256 + l15;
    const size_t ro1 = (size_t)(grow + 16 + quad * 4 + r) * 256 + l15;
#pragma unroll
    for (int ct = 0; ct < 16; ++ct) {
      Od[ro0 + ct * 16] = (f16)o0[ct][r];
      Od[ro1 + ct * 16] = (f16)o1[ct][r];
    }
  }
  if (lane < 16) {
    Mp[kz * NROWS + grow + l15] = m0;
    Lp[kz * NROWS + grow + l15] = l0;
    Mp[kz * NROWS + grow + 16 + l15] = m1;
    Lp[kz * NROWS + grow + 16 + l15] = l1;
  }
}

// ---------------------------------------------------------------------------
// Fused split-K merge + output projection. 512 blocks x 32 rows.
// B fragments read directly from L2 (fragment-ordered Wf); single barrier.
// ---------------------------------------------------------------------------
__global__ __launch_bounds__(256)
void oproj_mfma_kernel(const f16* __restrict__ Pp, const float* __restrict__ Mp,
                       const float* __restrict__ Lp, const f16* __restrict__ Wto,
                       const float* __restrict__ bo, float* __restrict__ out)
{
  __shared__ f16 xs[32][264];                   // 16.5 KB (padded)
  const int tid = threadIdx.x, lane = tid & 63, w = tid >> 6;
  const int l15 = lane & 15, quad = lane >> 4;
  const int rb = blockIdx.x * 32;

  // ---- merge prologue: 32 rows x 256 cols, 4-way split-K (exp2 domain)
  const int c4 = (tid & 63) * 4;
  const int rsub = tid >> 6;
#pragma unroll
  for (int e = 0; e < 8; ++e) {
    int rl = e * 4 + rsub;
    int row = rb + rl;
    float m[4], l[4];
#pragma unroll
    for (int z = 0; z < 4; ++z) {
      m[z] = Mp[z * NROWS + row];
      l[z] = Lp[z * NROWS + row];
    }
    float mm = fmaxf(fmaxf(m[0], m[1]), fmaxf(m[2], m[3]));
    float wz[4], denom = 0.f;
#pragma unroll
    for (int z = 0; z < 4; ++z) { wz[z] = EX2(m[z] - mm); denom += wz[z] * l[z]; }
    float inv = 1.0f / denom;
    float s0 = 0.f, s1 = 0.f, s2 = 0.f, s3 = 0.f;
#pragma unroll
    for (int z = 0; z < 4; ++z) {
      f16x4 h = *(const f16x4*)(Pp + (size_t)z * NE + (size_t)row * 256 + c4);
      s0 += wz[z] * (float)h[0];
      s1 += wz[z] * (float)h[1];
      s2 += wz[z] * (float)h[2];
      s3 += wz[z] * (float)h[3];
    }
    f16x4 xv;
    xv[0] = (f16)(s0 * inv); xv[1] = (f16)(s1 * inv);
    xv[2] = (f16)(s2 * inv); xv[3] = (f16)(s3 * inv);
    *(f16x4*)&xs[rl][c4] = xv;
  }
  __syncthreads();                       // xs ready

  // ---- GEMM: wave w -> rows (w&1)*16, ct group (w>>1)*8; B frags from L2
  const int rw = (w & 1) * 16;
  const int cg = (w >> 1) * 8;
  f32x4 acc[8];
#pragma unroll
  for (int c = 0; c < 8; ++c) acc[c] = (f32x4){0.f, 0.f, 0.f, 0.f};

#pragma unroll
  for (int kc = 0; kc < 8; ++kc) {
    f16x8 a = *(const f16x8*)&xs[rw + l15][kc * 32 + quad * 8];
#pragma unroll
    for (int c = 0; c < 8; ++c) {
      f16x8 b = *(const f16x8*)(Wto + (size_t)((cg + c) * 8 + kc) * 512 + lane * 8);
      acc[c] = MFMAH(a, b, acc[c]);
    }
  }

#pragma unroll
  for (int c = 0; c < 8; ++c) {
    int col = (cg + c) * 16 + l15;
    float bct = bo[col];
#pragma unroll
    for (int r = 0; r < 4; ++r)
      out[(size_t)(rb + rw + quad * 4 + r) * 256 + col] = acc[c][r] + bct;
  }
}

// ---------------------------------------------------------------------------
extern "C" void kernel_launch(void* const* d_in, const int* in_sizes, int n_in,
                              void* d_out, int out_size, void* d_ws, size_t ws_size,
                              hipStream_t stream)
{
  const float* inp = (const float*)d_in[0];
  const float* wq  = (const float*)d_in[1];
  const float* bq  = (const float*)d_in[2];
  const float* wk  = (const float*)d_in[3];
  const float* bk  = (const float*)d_in[4];
  const float* wv  = (const float*)d_in[5];
  const float* bv  = (const float*)d_in[6];
  const float* wo  = (const float*)d_in[7];
  const float* bo  = (const float*)d_in[8];
  float* out = (float*)d_out;

  // ws (~60 MB): Qh, Kf, Vf (NE f16), Wt (4*65536 f16 frag-ordered), Pp, m/l
  f16* Qh = (f16*)d_ws;
  f16* Kf = Qh + NE;
  f16* Vf = Kf + NE;
  f16* Wt = Vf + NE;
  f16* Pp = Wt + 4 * 65536;
  float* Mp = (float*)(Pp + 4 * NE);
  float* Lp = Mp + 4 * NROWS;

  prep_wt_kernel<<<dim3(32, 4), 256, 0, stream>>>(wq, wk, wv, wo, Wt);

  qkv_mfma_kernel<<<dim3(256, 3), 256, 0, stream>>>(
      inp, Wt, bq, bk, bv, Qh, Kf, Vf);

  attn6_kernel<<<512, 256, 0, stream>>>(Qh, (const char*)Kf, (const char*)Vf,
                                        Pp, Mp, Lp);

  oproj_mfma_kernel<<<512, 256, 0, stream>>>(Pp, Mp, Lp, Wt + 3 * 65536, bo, out);
}

// Round 6
// 215.477 us; speedup vs baseline: 1.1619x; 1.0038x over previous
//
#include <hip/hip_runtime.h>

typedef _Float16 f16;
typedef _Float16 f16x4 __attribute__((ext_vector_type(4)));
typedef _Float16 f16x8 __attribute__((ext_vector_type(8)));
typedef float f32x4  __attribute__((ext_vector_type(4)));

#define MFMAH(a, b, c) __builtin_amdgcn_mfma_f32_16x16x32_f16(a, b, c, 0, 0, 0)
#define EX2(x) __builtin_amdgcn_exp2f(x)

constexpr int D = 256;
constexpr int S = 4096;
constexpr int BATCH = 4;
constexpr int NROWS = BATCH * S;           // 16384
// softmax runs in exp2 domain: fold log2(e) into the Q scale.
constexpr float SCALE = 0.0625f * 1.44269504088896340736f;
constexpr float DTHR = 6.0f;               // defer-max threshold (log2 units): p <= 64
constexpr size_t NE = (size_t)NROWS * D;   // 4.19M elems

// async global->LDS: per-lane src addr, wave-uniform LDS base (+lane*16 by HW)
__device__ __forceinline__ void gll16(const void* g, void* l) {
  __builtin_amdgcn_global_load_lds(
      (const __attribute__((address_space(1))) unsigned int*)g,
      (__attribute__((address_space(3))) unsigned int*)l, 16, 0, 0);
}

// ---------------------------------------------------------------------------
// Prep: W in MFMA-fragment order. frag f = ct*8+kc (1KB each), lane-contiguous:
// Wf[m][f][lane][j] = w_m[(kc*32+quad*8+j)][ct*16+l15]   (fp16)
// A wave's B-fragment read is then ONE coalesced 1KB global_load_dwordx4
// (L2-resident, 128KB/m) -> qkv/oproj need no LDS staging and no barriers.
// ---------------------------------------------------------------------------
__global__ __launch_bounds__(256)
void prep_wt_kernel(const float* __restrict__ wq, const float* __restrict__ wk,
                    const float* __restrict__ wv, const float* __restrict__ wo,
                    f16* __restrict__ Wf)
{
  const int m = blockIdx.y;
  const float* w = (m == 0) ? wq : (m == 1) ? wk : (m == 2) ? wv : wo;
  int id = blockIdx.x * 256 + threadIdx.x;    // 0..8191 (one 16B chunk each)
  int f = id >> 6, lane = id & 63;
  int ct = f >> 3, kc = f & 7;
  int l15 = lane & 15, quad = lane >> 4;
  const float* src = w + (kc * 32 + quad * 8) * 256 + ct * 16 + l15;
  f16x8 v;
#pragma unroll
  for (int j = 0; j < 8; ++j) v[j] = (f16)src[j * 256];
  *(f16x8*)(Wf + ((size_t)m << 16) + (size_t)id * 8) = v;
}

// ---------------------------------------------------------------------------
// QKV projection via MFMA. B fragments read directly from L2 (fragment-ordered
// Wf) -> barrier-free main loop, fully compiler-pipelined. LDS used only for
// the transposed coalesced epilogues (r7-validated layouts).
// Q: row-major fp16, scaled by SCALE (exp2-domain softmax downstream).
// ---------------------------------------------------------------------------
__global__ __launch_bounds__(256)
void qkv_mfma_kernel(const float* __restrict__ in, const f16* __restrict__ Wt,
                     const float* __restrict__ bq, const float* __restrict__ bk,
                     const float* __restrict__ bv,
                     f16* __restrict__ Qh, f16* __restrict__ Kf, f16* __restrict__ Vf)
{
  __shared__ __align__(16) char smem[32768];   // epilogue transpose buffer
  const int m = blockIdx.y;
  const int tid = threadIdx.x, lane = tid & 63, w = tid >> 6;
  const int l15 = lane & 15, quad = lane >> 4;
  const int row0 = blockIdx.x * 64 + w * 16;
  const f16* Wm = Wt + ((size_t)m << 16);
  const float* bias = (m == 0) ? bq : (m == 1) ? bk : bv;

  // ---- A fragments: 16 rows of `in`, fp32 -> fp16 up front
  f16x8 af[8];
  {
    const float* arow = in + (size_t)(row0 + l15) * 768 + m * 256 + quad * 8;
#pragma unroll
    for (int kc = 0; kc < 8; ++kc) {
      float4 a0 = *(const float4*)(arow + kc * 32);
      float4 a1 = *(const float4*)(arow + kc * 32 + 4);
      f16x8 a;
      a[0] = (f16)a0.x; a[1] = (f16)a0.y; a[2] = (f16)a0.z; a[3] = (f16)a0.w;
      a[4] = (f16)a1.x; a[5] = (f16)a1.y; a[6] = (f16)a1.z; a[7] = (f16)a1.w;
      af[kc] = a;
    }
  }

  f32x4 acc[16];
#pragma unroll
  for (int ct = 0; ct < 16; ++ct) acc[ct] = (f32x4){0.f, 0.f, 0.f, 0.f};

  // ---- main loop: direct L2 B-frag loads, no barriers
#pragma unroll
  for (int kc = 0; kc < 8; ++kc) {
#pragma unroll
    for (int ct = 0; ct < 16; ++ct) {
      f16x8 b = *(const f16x8*)(Wm + (size_t)(ct * 8 + kc) * 512 + lane * 8);
      acc[ct] = MFMAH(af[kc], b, acc[ct]);
    }
  }

  const int b_ = row0 >> 12;

  if (m == 0) {
    f16* ws = (f16*)(smem + w * 8192);
#pragma unroll
    for (int ct = 0; ct < 16; ++ct) {
      float bct = bias[ct * 16 + l15];
#pragma unroll
      for (int r = 0; r < 4; ++r)
        ws[(quad * 4 + r) * 256 + ct * 16 + l15] = (f16)((acc[ct][r] + bct) * SCALE);
    }
    f16* dst = Qh + (size_t)row0 * 256;
#pragma unroll
    for (int i = 0; i < 8; ++i)
      *(uint4*)(dst + lane * 8 + i * 512) = *(const uint4*)(ws + lane * 8 + i * 512);
  } else if (m == 1) {
    f16* ws = (f16*)(smem + w * 8192);
#pragma unroll
    for (int ct = 0; ct < 16; ++ct) {
      float bct = bias[ct * 16 + l15];
      int base = (ct >> 1) * 512 + ((ct & 1) * 2 + (l15 >> 3)) * 128 + (l15 & 7);
#pragma unroll
      for (int r = 0; r < 4; ++r)
        ws[base + (quad * 4 + r) * 8] = (f16)(acc[ct][r] + bct);
    }
    const int g = (row0 & 4095) >> 4;
    f16* dst = Kf + ((size_t)(b_ * 256 + g)) * 8 * 512;
#pragma unroll
    for (int i = 0; i < 8; ++i)
      *(uint4*)(dst + lane * 8 + i * 512) = *(const uint4*)(ws + lane * 8 + i * 512);
  } else {
    const int t = w & 1;
    f16* ws = (f16*)(smem + (w >> 1) * 16384);
#pragma unroll
    for (int ct = 0; ct < 16; ++ct) {
      float bct = bias[ct * 16 + l15];
      int base = ct * 512 + quad * 128 + l15 * 8 + t * 4;
#pragma unroll
      for (int r = 0; r < 4; ++r)
        ws[base + r] = (f16)(acc[ct][r] + bct);
    }
    __syncthreads();
    const int gv0 = ((blockIdx.x * 64) & 4095) >> 5;
    f16* dst = Vf + ((size_t)(b_ * 128 + gv0)) * 16 * 512;
    const f16* src = (const f16*)smem;
#pragma unroll
    for (int i = 0; i < 8; ++i)
      *(uint4*)(dst + tid * 8 + i * 2048) = *(const uint4*)(src + tid * 8 + i * 2048);
  }
}

// ---------------------------------------------------------------------------
// fp16 MFMA flash attention. 512 blocks x 256 thr, split-K=4, 32-key tiles.
// exp2-domain softmax (log2e folded into Q scale), defer-max (rescale only
// when tile max exceeds running max by >DTHR; exact, p bounded by 2^DTHR=64),
// s_setprio(1) around MFMA clusters. Best-measured variant: 85.3us.
// Session note: four schedule variants (2-phase, shuffle-diet, V-from-L2,
// rotated pipeline) all land 85-88us except the register-wall regression;
// structural floor is the 32KB/wave/iter LDS read stream at 2 waves/SIMD
// (D=256 -> Q+O=192 persistent regs, K/V-in-reg time-share cannot fit).
// ---------------------------------------------------------------------------
__global__ __launch_bounds__(256, 2)
void attn6_kernel(const f16* __restrict__ Qh, const char* __restrict__ Kf,
                  const char* __restrict__ Vf,
                  f16* __restrict__ Pp, float* __restrict__ Mp, float* __restrict__ Lp)
{
  __shared__ __align__(16) char KVs[2][32768];   // [K 16 frags][V 16 frags]

  const int tid = threadIdx.x, lane = tid & 63, w = tid >> 6;
  const int l15 = lane & 15, quad = lane >> 4;

  const int bx    = blockIdx.x;
  const int combo = bx & 15;
  const int b     = combo & 3;
  const int kz    = combo >> 2;
  const int qb    = bx >> 4;                   // 0..31
  const int qrow0 = qb * 128 + w * 32;
  const int grow  = b * 4096 + qrow0;

  f16x8 qf[2][8];
#pragma unroll
  for (int sub = 0; sub < 2; ++sub) {
    const size_t qoff = (size_t)(grow + sub * 16 + l15) * 256 + quad * 8;
#pragma unroll
    for (int kc = 0; kc < 8; ++kc)
      qf[sub][kc] = *(const f16x8*)(Qh + qoff + kc * 32);
  }

  const char* kg[4];
  const char* vg[4];
#pragma unroll
  for (int i = 0; i < 4; ++i) {
    int f = 4 * w + i;
    kg[i] = Kf + (((size_t)(b * 256 + kz * 64 + (f >> 3))) * 8 + (f & 7)) * 1024
               + lane * 16;
    vg[i] = Vf + (((size_t)(b * 128 + kz * 32)) * 16 + f) * 1024 + lane * 16;
  }
  auto stage = [&](int buf) {
    char* base = &KVs[buf][0];
#pragma unroll
    for (int i = 0; i < 4; ++i) { gll16(kg[i], base + (4 * w + i) * 1024); kg[i] += 16384; }
#pragma unroll
    for (int i = 0; i < 4; ++i) { gll16(vg[i], base + 16384 + (4 * w + i) * 1024); vg[i] += 16384; }
  };

  f32x4 o0[16], o1[16];
#pragma unroll
  for (int ct = 0; ct < 16; ++ct) {
    o0[ct] = (f32x4){0.f, 0.f, 0.f, 0.f};
    o1[ct] = (f32x4){0.f, 0.f, 0.f, 0.f};
  }
  float m0 = -3.0e38f, m1 = -3.0e38f, l0 = 0.f, l1 = 0.f;

  stage(0);

  for (int it = 0; it < 32; ++it) {
    __syncthreads();
    if (it < 31) stage((it + 1) & 1);
    const char* Bf = &KVs[it & 1][0];

    f32x4 sA0 = (f32x4){0.f,0.f,0.f,0.f}, sB0 = (f32x4){0.f,0.f,0.f,0.f};
    f32x4 sA1 = (f32x4){0.f,0.f,0.f,0.f}, sB1 = (f32x4){0.f,0.f,0.f,0.f};
    __builtin_amdgcn_s_setprio(1);
#pragma unroll
    for (int kc = 0; kc < 8; ++kc) {
      f16x8 kA = *(const f16x8*)(Bf + kc * 1024 + lane * 16);
      f16x8 kB = *(const f16x8*)(Bf + 8192 + kc * 1024 + lane * 16);
      sA0 = MFMAH(kA, qf[0][kc], sA0);
      sA1 = MFMAH(kA, qf[1][kc], sA1);
      sB0 = MFMAH(kB, qf[0][kc], sB0);
      sB1 = MFMAH(kB, qf[1][kc], sB1);
    }
    __builtin_amdgcn_s_setprio(0);

    f16x8 ph0, ph1;
    {
      float t = fmaxf(fmaxf(fmaxf(sA0[0], sA0[1]), fmaxf(sA0[2], sA0[3])),
                      fmaxf(fmaxf(sB0[0], sB0[1]), fmaxf(sB0[2], sB0[3])));
      t = fmaxf(t, __shfl_xor(t, 16));
      t = fmaxf(t, __shfl_xor(t, 32));
      if (__any(t > m0 + DTHR)) {          // rare after iter 0 (defer-max)
        float mn = fmaxf(m0, t);
        float al = EX2(m0 - mn);
        float a0 = __shfl(al, (quad << 2) + 0);
        float a1 = __shfl(al, (quad << 2) + 1);
        float a2 = __shfl(al, (quad << 2) + 2);
        float a3 = __shfl(al, (quad << 2) + 3);
#pragma unroll
        for (int ct = 0; ct < 16; ++ct) {
          o0[ct][0] *= a0; o0[ct][1] *= a1; o0[ct][2] *= a2; o0[ct][3] *= a3;
        }
        l0 *= al;
        m0 = mn;
      }
      float ps = 0.f;
#pragma unroll
      for (int r = 0; r < 4; ++r) {
        float pa = EX2(sA0[r] - m0);
        float pb = EX2(sB0[r] - m0);
        ph0[r] = (f16)pa;  ph0[r + 4] = (f16)pb;
        ps += pa + pb;
      }
      ps += __shfl_xor(ps, 16);
      ps += __shfl_xor(ps, 32);
      l0 += ps;
    }
    {
      float t = fmaxf(fmaxf(fmaxf(sA1[0], sA1[1]), fmaxf(sA1[2], sA1[3])),
                      fmaxf(fmaxf(sB1[0], sB1[1]), fmaxf(sB1[2], sB1[3])));
      t = fmaxf(t, __shfl_xor(t, 16));
      t = fmaxf(t, __shfl_xor(t, 32));
      if (__any(t > m1 + DTHR)) {          // rare after iter 0 (defer-max)
        float mn = fmaxf(m1, t);
        float al = EX2(m1 - mn);
        float a0 = __shfl(al, (quad << 2) + 0);
        float a1 = __shfl(al, (quad << 2) + 1);
        float a2 = __shfl(al, (quad << 2) + 2);
        float a3 = __shfl(al, (quad << 2) + 3);
#pragma unroll
        for (int ct = 0; ct < 16; ++ct) {
          o1[ct][0] *= a0; o1[ct][1] *= a1; o1[ct][2] *= a2; o1[ct][3] *= a3;
        }
        l1 *= al;
        m1 = mn;
      }
      float ps = 0.f;
#pragma unroll
      for (int r = 0; r < 4; ++r) {
        float pa = EX2(sA1[r] - m1);
        float pb = EX2(sB1[r] - m1);
        ph1[r] = (f16)pa;  ph1[r + 4] = (f16)pb;
        ps += pa + pb;
      }
      ps += __shfl_xor(ps, 16);
      ps += __shfl_xor(ps, 32);
      l1 += ps;
    }

    __builtin_amdgcn_s_setprio(1);
#pragma unroll
    for (int ct = 0; ct < 16; ++ct) {
      f16x8 vf = *(const f16x8*)(Bf + 16384 + ct * 1024 + lane * 16);
      o0[ct] = MFMAH(ph0, vf, o0[ct]);
      o1[ct] = MFMAH(ph1, vf, o1[ct]);
    }
    __builtin_amdgcn_s_setprio(0);
  }

  f16* Od = Pp + (size_t)kz * NE;
#pragma unroll
  for (int r = 0; r < 4; ++r) {
    const size_t ro0 = (size_t)(grow + quad * 4 + r) * 256 + l15;
    const size_t ro1 = (size_t)(grow + 16 + quad * 4 + r) * 256 + l15;
#pragma unroll
    for (int ct = 0; ct < 16; ++ct) {
      Od[ro0 + ct * 16] = (f16)o0[ct][r];
      Od[ro1 + ct * 16] = (f16)o1[ct][r];
    }
  }
  if (lane < 16) {
    Mp[kz * NROWS + grow + l15] = m0;
    Lp[kz * NROWS + grow + l15] = l0;
    Mp[kz * NROWS + grow + 16 + l15] = m1;
    Lp[kz * NROWS + grow + 16 + l15] = l1;
  }
}

// ---------------------------------------------------------------------------
// Fused split-K merge + output projection. 512 blocks x 32 rows.
// B fragments read directly from L2 (fragment-ordered Wf) -> single barrier
// (merge->GEMM); no staging. Merge weights in exp2 domain.
// ---------------------------------------------------------------------------
__global__ __launch_bounds__(256)
void oproj_mfma_kernel(const f16* __restrict__ Pp, const float* __restrict__ Mp,
                       const float* __restrict__ Lp, const f16* __restrict__ Wto,
                       const float* __restrict__ bo, float* __restrict__ out)
{
  __shared__ f16 xs[32][264];                   // 16.5 KB (padded)
  const int tid = threadIdx.x, lane = tid & 63, w = tid >> 6;
  const int l15 = lane & 15, quad = lane >> 4;
  const int rb = blockIdx.x * 32;

  // ---- merge prologue: 32 rows x 256 cols, 4-way split-K (exp2 domain)
  const int c4 = (tid & 63) * 4;
  const int rsub = tid >> 6;
#pragma unroll
  for (int e = 0; e < 8; ++e) {
    int rl = e * 4 + rsub;
    int row = rb + rl;
    float m[4], l[4];
#pragma unroll
    for (int z = 0; z < 4; ++z) {
      m[z] = Mp[z * NROWS + row];
      l[z] = Lp[z * NROWS + row];
    }
    float mm = fmaxf(fmaxf(m[0], m[1]), fmaxf(m[2], m[3]));
    float wz[4], denom = 0.f;
#pragma unroll
    for (int z = 0; z < 4; ++z) { wz[z] = EX2(m[z] - mm); denom += wz[z] * l[z]; }
    float inv = 1.0f / denom;
    float s0 = 0.f, s1 = 0.f, s2 = 0.f, s3 = 0.f;
#pragma unroll
    for (int z = 0; z < 4; ++z) {
      f16x4 h = *(const f16x4*)(Pp + (size_t)z * NE + (size_t)row * 256 + c4);
      s0 += wz[z] * (float)h[0];
      s1 += wz[z] * (float)h[1];
      s2 += wz[z] * (float)h[2];
      s3 += wz[z] * (float)h[3];
    }
    f16x4 xv;
    xv[0] = (f16)(s0 * inv); xv[1] = (f16)(s1 * inv);
    xv[2] = (f16)(s2 * inv); xv[3] = (f16)(s3 * inv);
    *(f16x4*)&xs[rl][c4] = xv;
  }
  __syncthreads();                       // xs ready

  // ---- GEMM: wave w -> rows (w&1)*16, ct group (w>>1)*8; B frags from L2
  const int rw = (w & 1) * 16;
  const int cg = (w >> 1) * 8;
  f32x4 acc[8];
#pragma unroll
  for (int c = 0; c < 8; ++c) acc[c] = (f32x4){0.f, 0.f, 0.f, 0.f};

#pragma unroll
  for (int kc = 0; kc < 8; ++kc) {
    f16x8 a = *(const f16x8*)&xs[rw + l15][kc * 32 + quad * 8];
#pragma unroll
    for (int c = 0; c < 8; ++c) {
      f16x8 b = *(const f16x8*)(Wto + (size_t)((cg + c) * 8 + kc) * 512 + lane * 8);
      acc[c] = MFMAH(a, b, acc[c]);
    }
  }

#pragma unroll
  for (int c = 0; c < 8; ++c) {
    int col = (cg + c) * 16 + l15;
    float bct = bo[col];
#pragma unroll
    for (int r = 0; r < 4; ++r)
      out[(size_t)(rb + rw + quad * 4 + r) * 256 + col] = acc[c][r] + bct;
  }
}

// ---------------------------------------------------------------------------
extern "C" void kernel_launch(void* const* d_in, const int* in_sizes, int n_in,
                              void* d_out, int out_size, void* d_ws, size_t ws_size,
                              hipStream_t stream)
{
  const float* inp = (const float*)d_in[0];
  const float* wq  = (const float*)d_in[1];
  const float* bq  = (const float*)d_in[2];
  const float* wk  = (const float*)d_in[3];
  const float* bk  = (const float*)d_in[4];
  const float* wv  = (const float*)d_in[5];
  const float* bv  = (const float*)d_in[6];
  const float* wo  = (const float*)d_in[7];
  const float* bo  = (const float*)d_in[8];
  float* out = (float*)d_out;

  // ws (~60 MB): Qh, Kf, Vf (NE f16), Wt (4*65536 f16 frag-ordered), Pp, m/l
  f16* Qh = (f16*)d_ws;
  f16* Kf = Qh + NE;
  f16* Vf = Kf + NE;
  f16* Wt = Vf + NE;
  f16* Pp = Wt + 4 * 65536;
  float* Mp = (float*)(Pp + 4 * NE);
  float* Lp = Mp + 4 * NROWS;

  prep_wt_kernel<<<dim3(32, 4), 256, 0, stream>>>(wq, wk, wv, wo, Wt);

  qkv_mfma_kernel<<<dim3(256, 3), 256, 0, stream>>>(
      inp, Wt, bq, bk, bv, Qh, Kf, Vf);

  attn6_kernel<<<512, 256, 0, stream>>>(Qh, (const char*)Kf, (const char*)Vf,
                                        Pp, Mp, Lp);

  oproj_mfma_kernel<<<512, 256, 0, stream>>>(Pp, Mp, Lp, Wt + 3 * 65536, bo, out);
}